// Round 5
// baseline (11476.707 us; speedup 1.0000x reference)
//
#include <hip/hip_runtime.h>

// GRU L=512, N=64, H=512, E=256, K=H+E=768. Persistent column-split kernel:
// 32 blocks x 256 threads; block b owns 16 output cols of z/r/h~; fp16 weight
// slices LDS-resident (73.7 KB, XOR-swizzled).
// Round 5: tagged-unit dataflow exchange, publication == data store.
//  - exchange unit: u64 = (generation tag << 32) | 2 packed fp16 cols.
//    Producers: relaxed agent-scope 64-bit atomic stores (write-through to
//    coherence point). NO flag, NO vmcnt drain before publish.
//  - consumers: bulk-load their 64-unit panel once (pipelined relaxed agent
//    loads); scan tags in registers; retry reloads ONLY stale units
//    (exec-masked per-unit loads) -- fixes round 3's full-panel repoll
//    (850 MB refetch, 15.4 ms).
//  - ordering: each wave's gen-T+1 stores depend (register dataflow) on its
//    gen-T loads, and inter-block dependence is transitive through the tags,
//    so single-buffering is race- and deadlock-free (round-3-verified).
//  - schedule per step: r e-part | consume h | r h-part | publish r*h |
//    z matmul (h frags in regs) + z,h~ e-parts | consume r*h | h~ h-part |
//    epilogue | publish h.
// Numerics: fp16 operands, f32 MFMA accum, f32 state (measured absmax 3.9e-3).

#define LSTEPS 512
#define NBATCH 64
#define HDIM   512
#define EDIM   256
#define KDIM   768
#define NBLK   32
#define TPB    256

typedef _Float16 f16x8 __attribute__((ext_vector_type(8)));
typedef float    f32x4 __attribute__((ext_vector_type(4)));
typedef unsigned long long u64;

__device__ __forceinline__ float sigm(float x){ return 1.0f/(1.0f+__expf(-x)); }
__device__ __forceinline__ float tanh_fast(float x){
  float e = __expf(2.0f*x);
  return 1.0f - 2.0f/(e + 1.0f);
}
__device__ __forceinline__ unsigned f16b(float x){
  union { _Float16 h; unsigned short u; } c; c.h = (_Float16)x; return (unsigned)c.u;
}

// Transpose+convert weights: wbuf[g][j][k] = fp16(W_g[k][j]); g in {z,r,h}.
__global__ void prep_w(const float* __restrict__ Wz, const float* __restrict__ Wr,
                       const float* __restrict__ Wh, _Float16* __restrict__ wbuf){
  int tid = blockIdx.x*256 + threadIdx.x;        // 3*512*768 = 1179648 threads
  int g   = tid / (HDIM*KDIM);
  int rem = tid - g*(HDIM*KDIM);
  int j   = rem / KDIM;
  int k   = rem - j*KDIM;
  const float* W = (g==0) ? Wz : ((g==1) ? Wr : Wh);
  wbuf[tid] = (_Float16)W[(size_t)k*HDIM + j];
}

// Gather embedding rows + convert: ebuf[t][n][k] = fp16(emb[x[t][n]][k]).
__global__ void prep_emb(const int* __restrict__ x, const float* __restrict__ emb,
                         _Float16* __restrict__ ebuf){
  int tid = blockIdx.x*256 + threadIdx.x;        // one float4 each
  int k4  = tid & 63;                            // E/4 = 64
  int tn  = tid >> 6;                            // 0..L*N-1
  int row = x[tn];
  const float4 v = *(const float4*)(emb + (size_t)row*EDIM + (k4<<2));
  union { _Float16 h[4]; uint2 u; } p;
  p.h[0] = (_Float16)v.x; p.h[1] = (_Float16)v.y;
  p.h[2] = (_Float16)v.z; p.h[3] = (_Float16)v.w;
  *(uint2*)(ebuf + (size_t)tn*EDIM + (k4<<2)) = p.u;
}

// Tagged exchange store of (rows n0..n0+3, col jcol) -> [64][256] u64 units.
// Lane pair (2q,2q+1) covers cols (j,j+1): shfl_xor repack -> even lane
// stores rows n0..n0+1, odd lane rows n0+2..n0+3, each one 8B unit
// (hi32 = tag, lo32 = fp16 pair). Relaxed agent atomics = write-through.
__device__ __forceinline__ void store_tagged(u64* buf, int jc2u, int n0, int lane,
                                             unsigned tag,
                                             float v0, float v1, float v2, float v3){
  unsigned p01 = f16b(v0) | (f16b(v1) << 16);
  unsigned p23 = f16b(v2) | (f16b(v3) << 16);
  unsigned q01 = __shfl_xor(p01, 1, 64);
  unsigned q23 = __shfl_xor(p23, 1, 64);
  unsigned w0, w1; int r0;
  if (lane & 1){                       // own col = j+1 (high half of pair)
    w0 = (q23 & 0xffffu) | (p23 << 16);
    w1 = (q23 >> 16)     | (p23 & 0xffff0000u);
    r0 = n0 + 2;
  } else {                             // own col = j (low half)
    w0 = (p01 & 0xffffu) | (q01 << 16);
    w1 = (p01 >> 16)     | (q01 & 0xffff0000u);
    r0 = n0;
  }
  u64 t64 = ((u64)tag) << 32;
  __hip_atomic_store(buf + (size_t)r0*256 + jc2u,     t64 | (u64)w0,
                     __ATOMIC_RELAXED, __HIP_MEMORY_SCOPE_AGENT);
  __hip_atomic_store(buf + (size_t)(r0+1)*256 + jc2u, t64 | (u64)w1,
                     __ATOMIC_RELAXED, __HIP_MEMORY_SCOPE_AGENT);
}

__global__ __launch_bounds__(TPB, 1) void gru_persist(
    const _Float16* __restrict__ wbuf,   // [3][512][768] fp16 (col-major per gate)
    const _Float16* __restrict__ ebuf,   // [L][64][256] fp16
    const float* __restrict__ bz, const float* __restrict__ br, const float* __restrict__ bh,
    u64* __restrict__ hx,                // [64][256] tagged h units
    u64* __restrict__ rhx,               // [64][256] tagged r*h units
    float* __restrict__ out)             // [L][64][512] f32
{
  __shared__ char wlds[3*16*1536];       // 73728 B: [gate][col16][768 fp16]
  const int jbase = blockIdx.x * 16;

  // Stage weight slices -> LDS, XOR-swizzled by col to spread banks.
  for (int cidx = threadIdx.x; cidx < 3*16*96; cidx += TPB){
    int g   = cidx / (16*96);
    int rem = cidx - g*(16*96);
    int col = rem / 96;
    int kch = rem - col*96;              // 16B chunk index along K
    const uint4 v = *(const uint4*)(wbuf + ((size_t)(g*HDIM + jbase + col))*KDIM + kch*8);
    int off = (((g*16 + col)*1536) + kch*16) ^ ((col & 7) << 4);
    *(uint4*)(wlds + off) = v;
  }
  __syncthreads();                       // only barrier; loop below is per-wave

  const int lane = threadIdx.x & 63;
  const int wave = threadIdx.x >> 6;     // M-tile: rows 16*wave..16*wave+15
  const int c15  = lane & 15;
  const int kgrp = lane >> 4;
  const int jcol = jbase + c15;
  const int jc2u = jcol >> 1;            // u64 unit index of own col pair
  const int arow = wave*16 + c15;        // A-fragment row (batch)
  const int n0   = wave*16 + kgrp*4;     // C/D row base (batch)
  const int swz  = (c15 & 7) << 4;
  const int linz = ((      c15)*1536) + kgrp*16;
  const int linr = ((16  + c15)*1536) + kgrp*16;
  const int linh = ((32  + c15)*1536) + kgrp*16;
  const float bzj = bz[jcol];
  const float brj = br[jcol];
  const float bhj = bh[jcol];
  const u64* hrow  = hx  + (size_t)arow*256 + kgrp*4;   // + kc*16 + i
  const u64* rhrow = rhx + (size_t)arow*256 + kgrp*4;
  float hreg[4] = {0.f, 0.f, 0.f, 0.f};  // private f32 hidden state

  u64 q[64];                              // tagged A-panel (128 VGPRs)

  // Bulk load: 64 pipelined relaxed agent loads (readiness travels with data).
#define LOADQ(BASE) do {                                                      \
    _Pragma("unroll")                                                         \
    for (int kc = 0; kc < 16; ++kc){                                          \
      _Pragma("unroll")                                                       \
      for (int i = 0; i < 4; ++i)                                             \
        q[kc*4+i] = __hip_atomic_load((BASE) + kc*16 + i,                     \
                      __ATOMIC_RELAXED, __HIP_MEMORY_SCOPE_AGENT);            \
    }                                                                         \
  } while (0)

  // Wait: scan tags; reload ONLY stale units until the whole wave is clean.
#define WAITQ(BASE, TAG) do {                                                 \
    for (;;){                                                                 \
      unsigned _bad = 0;                                                      \
      _Pragma("unroll")                                                       \
      for (int j = 0; j < 64; ++j) _bad |= ((unsigned)(q[j] >> 32)) ^ (TAG);  \
      if (!__any(_bad != 0)) break;                                           \
      _Pragma("unroll")                                                       \
      for (int j = 0; j < 64; ++j){                                           \
        if ((unsigned)(q[j] >> 32) != (TAG))                                  \
          q[j] = __hip_atomic_load((BASE) + (j>>2)*16 + (j&3),                \
                   __ATOMIC_RELAXED, __HIP_MEMORY_SCOPE_AGENT);               \
      }                                                                       \
    }                                                                         \
  } while (0)

#define AFRAG(KC) ({ union { unsigned u[4]; f16x8 v; } _a;                    \
                     _a.u[0] = (unsigned)q[(KC)*4+0];                         \
                     _a.u[1] = (unsigned)q[(KC)*4+1];                         \
                     _a.u[2] = (unsigned)q[(KC)*4+2];                         \
                     _a.u[3] = (unsigned)q[(KC)*4+3]; _a.v; })

  for (int t = 0; t < LSTEPS; ++t){
    const _Float16* ae = ebuf + ((size_t)t*NBATCH + arow)*EDIM + kgrp*8;
    const unsigned tago = (unsigned)t;        // h generation consumed
    const unsigned tagn = (unsigned)(t + 1);  // generation produced

    // ---- r gate: e-part first (independent), then consume h, h-part.
    f32x4 accr = {0.f,0.f,0.f,0.f};
    LOADQ(hrow);                         // in flight under the e-part
    #pragma unroll
    for (int kc = 0; kc < 8; ++kc){
      f16x8 a   = *(const f16x8*)(ae + kc*32);
      f16x8 brv = *(const f16x8*)(wlds + ((linr + (16+kc)*64) ^ swz));
      accr = __builtin_amdgcn_mfma_f32_16x16x32_f16(a, brv, accr, 0, 0, 0);
    }
    WAITQ(hrow, tago);                   // t=0: memset tags = 0, h = 0
    #pragma unroll
    for (int kc = 0; kc < 16; ++kc){
      f16x8 brv = *(const f16x8*)(wlds + ((linr + kc*64) ^ swz));
      accr = __builtin_amdgcn_mfma_f32_16x16x32_f16(AFRAG(kc), brv, accr, 0, 0, 0);
    }
    float rh[4];
    #pragma unroll
    for (int i = 0; i < 4; ++i)
      rh[i] = sigm(accr[i] + brj) * hreg[i];
    store_tagged(rhx, jc2u, n0, lane, tagn, rh[0], rh[1], rh[2], rh[3]);

    // ---- cover the rh round-trip: z matmul (h frags in regs) + e-parts.
    f32x4 accz = {0.f,0.f,0.f,0.f};
    f32x4 acch = {0.f,0.f,0.f,0.f};
    #pragma unroll
    for (int kc = 0; kc < 16; ++kc){
      f16x8 bzv = *(const f16x8*)(wlds + ((linz + kc*64) ^ swz));
      accz = __builtin_amdgcn_mfma_f32_16x16x32_f16(AFRAG(kc), bzv, accz, 0, 0, 0);
    }
    #pragma unroll
    for (int kc = 0; kc < 8; ++kc){
      f16x8 a   = *(const f16x8*)(ae + kc*32);
      f16x8 bzv = *(const f16x8*)(wlds + ((linz + (16+kc)*64) ^ swz));
      f16x8 bhv = *(const f16x8*)(wlds + ((linh + (16+kc)*64) ^ swz));
      accz = __builtin_amdgcn_mfma_f32_16x16x32_f16(a, bzv, accz, 0, 0, 0);
      acch = __builtin_amdgcn_mfma_f32_16x16x32_f16(a, bhv, acch, 0, 0, 0);
    }
    float zreg[4];
    #pragma unroll
    for (int i = 0; i < 4; ++i) zreg[i] = sigm(accz[i] + bzj);

    // ---- h~: consume r*h, h-part, epilogue, publish h.
    LOADQ(rhrow);
    WAITQ(rhrow, tagn);
    #pragma unroll
    for (int kc = 0; kc < 16; ++kc){
      f16x8 bhv = *(const f16x8*)(wlds + ((linh + kc*64) ^ swz));
      acch = __builtin_amdgcn_mfma_f32_16x16x32_f16(AFRAG(kc), bhv, acch, 0, 0, 0);
    }
    #pragma unroll
    for (int i = 0; i < 4; ++i){
      float ht = tanh_fast(acch[i] + bhj);
      float hn = hreg[i] + zreg[i]*(ht - hreg[i]);   // (1-z)h + z*h~
      hreg[i] = hn;
      out[((size_t)t*NBATCH + (n0+i))*HDIM + jcol] = hn;
    }
    store_tagged(hx, jc2u, n0, lane, tagn, hreg[0], hreg[1], hreg[2], hreg[3]);
  }
#undef LOADQ
#undef WAITQ
#undef AFRAG
}

extern "C" void kernel_launch(void* const* d_in, const int* in_sizes, int n_in,
                              void* d_out, int out_size, void* d_ws, size_t ws_size,
                              hipStream_t stream) {
  const int*   x   = (const int*)  d_in[0];
  const float* emb = (const float*)d_in[1];
  const float* Wz  = (const float*)d_in[2];
  const float* bz  = (const float*)d_in[3];
  const float* Wr  = (const float*)d_in[4];
  const float* br  = (const float*)d_in[5];
  const float* Wh  = (const float*)d_in[6];
  const float* bh  = (const float*)d_in[7];
  float* out = (float*)d_out;
  char*  ws  = (char*)d_ws;

  size_t off = 0;
  u64* hx  = (u64*)(ws + off); off += (size_t)NBATCH*(HDIM/2)*8;   // 131072
  u64* rhx = (u64*)(ws + off); off += (size_t)NBATCH*(HDIM/2)*8;   // 131072
  size_t zero_bytes = off;               // tags must start at 0 every launch
  _Float16* wbuf = (_Float16*)(ws + off); off += (size_t)3*HDIM*KDIM*2;        // 2359296
  _Float16* ebuf = (_Float16*)(ws + off); off += (size_t)LSTEPS*NBATCH*EDIM*2; // 16777216

  hipMemsetAsync(ws, 0, zero_bytes, stream);

  prep_w  <<<(3*HDIM*KDIM)/256,          256, 0, stream>>>(Wz, Wr, Wh, wbuf);
  prep_emb<<<(LSTEPS*NBATCH*EDIM/4)/256, 256, 0, stream>>>(x, emb, ebuf);
  gru_persist<<<NBLK, TPB, 0, stream>>>(wbuf, ebuf, bz, br, bh, hx, rhx, out);
}

// Round 6
// 8942.126 us; speedup vs baseline: 1.2834x; 1.2834x over previous
//
#include <hip/hip_runtime.h>

// GRU L=512, N=64, H=512, E=256, K=H+E=768.
// Round 6: sync through the GRAPH, not through memory. Two kernels per step,
// 1024 launches total, all captured/replayed by the harness's graph:
//   P1(t): z,r gates for own 16 cols (A = [h(t), e(t)]); writes z (f32) and
//          r*h (fp16) exchange.
//   P2(t): h~ for own cols (A = [r*h, e(t)]); h_new = (1-z)h + z h~;
//          writes hf (f32 state), hx (fp16 exchange), out[t].
// Kernel boundaries provide the grid barrier AND agent-scope release/acquire
// (HSA dispatch semantics), so ALL exchange buffers use plain loads/stores:
// no atomics, no flags, no spinning, no deadlock risk, no MALL round-trip
// protocol. Calibration from rounds 1-5: in-kernel MALL exchange ~4.8 us per
// phase; graphed launch boundary ~1.5-2.5 us.
// No LDS: each block's 73.7 KB weight slice is read from L1/L2 every launch
// (stays hot in its XCD's L2; per-phase slice read is 25-49 KB).
// Numerics: fp16 operands, f32 MFMA accum, f32 state (absmax 3.9e-3, rounds
// 1-5).

#define LSTEPS 512
#define NBATCH 64
#define HDIM   512
#define EDIM   256
#define KDIM   768
#define NBLK   32
#define TPB    256

typedef _Float16 f16x8 __attribute__((ext_vector_type(8)));
typedef float    f32x4 __attribute__((ext_vector_type(4)));

__device__ __forceinline__ float sigm(float x){ return 1.0f/(1.0f+__expf(-x)); }
__device__ __forceinline__ float tanh_fast(float x){
  float e = __expf(2.0f*x);
  return 1.0f - 2.0f/(e + 1.0f);
}

// Transpose+convert weights: wbuf[g][j][k] = fp16(W_g[k][j]); g in {z,r,h}.
__global__ void prep_w(const float* __restrict__ Wz, const float* __restrict__ Wr,
                       const float* __restrict__ Wh, _Float16* __restrict__ wbuf){
  int tid = blockIdx.x*256 + threadIdx.x;        // 3*512*768 = 1179648 threads
  int g   = tid / (HDIM*KDIM);
  int rem = tid - g*(HDIM*KDIM);
  int j   = rem / KDIM;
  int k   = rem - j*KDIM;
  const float* W = (g==0) ? Wz : ((g==1) ? Wr : Wh);
  wbuf[tid] = (_Float16)W[(size_t)k*HDIM + j];
}

// Gather embedding rows + convert: ebuf[t][n][k] = fp16(emb[x[t][n]][k]).
__global__ void prep_emb(const int* __restrict__ x, const float* __restrict__ emb,
                         _Float16* __restrict__ ebuf){
  int tid = blockIdx.x*256 + threadIdx.x;        // one float4 each
  int k4  = tid & 63;                            // E/4 = 64
  int tn  = tid >> 6;                            // 0..L*N-1
  int row = x[tn];
  const float4 v = *(const float4*)(emb + (size_t)row*EDIM + (k4<<2));
  union { _Float16 h[4]; uint2 u; } p;
  p.h[0] = (_Float16)v.x; p.h[1] = (_Float16)v.y;
  p.h[2] = (_Float16)v.z; p.h[3] = (_Float16)v.w;
  *(uint2*)(ebuf + (size_t)tn*EDIM + (k4<<2)) = p.u;
}

// Common per-thread geometry: 32 blocks x 4 waves; wave w = batch rows
// [16w,16w+16); block owns cols [16*bid, 16*bid+16).
//  lane = (c15, kgrp): A-frag row arow = 16w + c15, A cols kc*32+kgrp*8..+8;
//  B-frag: wbuf[g][jbase+c15][kc*32+kgrp*8..+8]; C/D rows n0 = 16w+4*kgrp.

__global__ __launch_bounds__(TPB) void gru_p1(
    const _Float16* __restrict__ wbuf,   // [3][512][768]
    const _Float16* __restrict__ ebuf,   // [L][64][256]
    const _Float16* __restrict__ hx,     // [64][512] fp16 h(t)
    const float* __restrict__ hf,        // [64][512] f32 h(t)
    const float* __restrict__ bz, const float* __restrict__ br,
    float* __restrict__ zbuf,            // [64][512] f32 z out (own cols)
    _Float16* __restrict__ rhx,          // [64][512] fp16 r*h out
    int t)
{
  const int lane = threadIdx.x & 63;
  const int wave = threadIdx.x >> 6;
  const int c15  = lane & 15;
  const int kgrp = lane >> 4;
  const int jcol = blockIdx.x*16 + c15;
  const int arow = wave*16 + c15;
  const int n0   = wave*16 + kgrp*4;
  const _Float16* ah = hx + (size_t)arow*HDIM + kgrp*8;
  const _Float16* ae = ebuf + ((size_t)t*NBATCH + arow)*EDIM + kgrp*8;
  const _Float16* wz = wbuf + (size_t)(0*HDIM + jcol)*KDIM + kgrp*8;
  const _Float16* wr = wbuf + (size_t)(1*HDIM + jcol)*KDIM + kgrp*8;

  f32x4 accz = {0.f,0.f,0.f,0.f};
  f32x4 accr = {0.f,0.f,0.f,0.f};
  #pragma unroll
  for (int kc = 0; kc < 16; ++kc){       // h-part (K = 0..512)
    f16x8 a   = *(const f16x8*)(ah + kc*32);
    f16x8 bzv = *(const f16x8*)(wz + kc*32);
    f16x8 brv = *(const f16x8*)(wr + kc*32);
    accz = __builtin_amdgcn_mfma_f32_16x16x32_f16(a, bzv, accz, 0, 0, 0);
    accr = __builtin_amdgcn_mfma_f32_16x16x32_f16(a, brv, accr, 0, 0, 0);
  }
  #pragma unroll
  for (int kc = 0; kc < 8; ++kc){        // e-part (K = 512..768)
    f16x8 a   = *(const f16x8*)(ae + kc*32);
    f16x8 bzv = *(const f16x8*)(wz + (16+kc)*32);
    f16x8 brv = *(const f16x8*)(wr + (16+kc)*32);
    accz = __builtin_amdgcn_mfma_f32_16x16x32_f16(a, bzv, accz, 0, 0, 0);
    accr = __builtin_amdgcn_mfma_f32_16x16x32_f16(a, brv, accr, 0, 0, 0);
  }
  const float bzj = bz[jcol];
  const float brj = br[jcol];
  #pragma unroll
  for (int i = 0; i < 4; ++i){
    int n = n0 + i;
    float hp = hf[(size_t)n*HDIM + jcol];
    zbuf[(size_t)n*HDIM + jcol] = sigm(accz[i] + bzj);
    rhx [(size_t)n*HDIM + jcol] = (_Float16)(sigm(accr[i] + brj) * hp);
  }
}

__global__ __launch_bounds__(TPB) void gru_p2(
    const _Float16* __restrict__ wbuf,
    const _Float16* __restrict__ ebuf,
    const _Float16* __restrict__ rhx,    // [64][512] fp16 r*h
    const float* __restrict__ zbuf,      // [64][512] f32 z
    const float* __restrict__ bh,
    float* __restrict__ hf,              // [64][512] f32 state (read+write)
    _Float16* __restrict__ hx,           // [64][512] fp16 h(t+1) out
    float* __restrict__ out,             // [L][64][512]
    int t)
{
  const int lane = threadIdx.x & 63;
  const int wave = threadIdx.x >> 6;
  const int c15  = lane & 15;
  const int kgrp = lane >> 4;
  const int jcol = blockIdx.x*16 + c15;
  const int arow = wave*16 + c15;
  const int n0   = wave*16 + kgrp*4;
  const _Float16* ar = rhx + (size_t)arow*HDIM + kgrp*8;
  const _Float16* ae = ebuf + ((size_t)t*NBATCH + arow)*EDIM + kgrp*8;
  const _Float16* wh = wbuf + (size_t)(2*HDIM + jcol)*KDIM + kgrp*8;

  f32x4 acch = {0.f,0.f,0.f,0.f};
  #pragma unroll
  for (int kc = 0; kc < 16; ++kc){       // rh-part
    f16x8 a   = *(const f16x8*)(ar + kc*32);
    f16x8 bhv = *(const f16x8*)(wh + kc*32);
    acch = __builtin_amdgcn_mfma_f32_16x16x32_f16(a, bhv, acch, 0, 0, 0);
  }
  #pragma unroll
  for (int kc = 0; kc < 8; ++kc){        // e-part
    f16x8 a   = *(const f16x8*)(ae + kc*32);
    f16x8 bhv = *(const f16x8*)(wh + (16+kc)*32);
    acch = __builtin_amdgcn_mfma_f32_16x16x32_f16(a, bhv, acch, 0, 0, 0);
  }
  const float bhj = bh[jcol];
  #pragma unroll
  for (int i = 0; i < 4; ++i){
    int n = n0 + i;
    float ht = tanh_fast(acch[i] + bhj);
    float hp = hf[(size_t)n*HDIM + jcol];
    float z  = zbuf[(size_t)n*HDIM + jcol];
    float hn = hp + z*(ht - hp);         // (1-z)h + z*h~
    hf[(size_t)n*HDIM + jcol] = hn;
    hx[(size_t)n*HDIM + jcol] = (_Float16)hn;
    out[((size_t)t*NBATCH + n)*HDIM + jcol] = hn;
  }
}

extern "C" void kernel_launch(void* const* d_in, const int* in_sizes, int n_in,
                              void* d_out, int out_size, void* d_ws, size_t ws_size,
                              hipStream_t stream) {
  const int*   x   = (const int*)  d_in[0];
  const float* emb = (const float*)d_in[1];
  const float* Wz  = (const float*)d_in[2];
  const float* bz  = (const float*)d_in[3];
  const float* Wr  = (const float*)d_in[4];
  const float* br  = (const float*)d_in[5];
  const float* Wh  = (const float*)d_in[6];
  const float* bh  = (const float*)d_in[7];
  float* out = (float*)d_out;
  char*  ws  = (char*)d_ws;

  size_t off = 0;
  _Float16* hx   = (_Float16*)(ws + off); off += (size_t)NBATCH*HDIM*2;     // 65536
  float*    hf   = (float*)   (ws + off); off += (size_t)NBATCH*HDIM*4;     // 131072
  size_t zero_bytes = off;               // h state must start at 0
  _Float16* rhx  = (_Float16*)(ws + off); off += (size_t)NBATCH*HDIM*2;     // 65536
  float*    zbuf = (float*)   (ws + off); off += (size_t)NBATCH*HDIM*4;     // 131072
  _Float16* wbuf = (_Float16*)(ws + off); off += (size_t)3*HDIM*KDIM*2;     // 2359296
  _Float16* ebuf = (_Float16*)(ws + off); off += (size_t)LSTEPS*NBATCH*EDIM*2; // 16777216

  hipMemsetAsync(ws, 0, zero_bytes, stream);

  prep_w  <<<(3*HDIM*KDIM)/256,          256, 0, stream>>>(Wz, Wr, Wh, wbuf);
  prep_emb<<<(LSTEPS*NBATCH*EDIM/4)/256, 256, 0, stream>>>(x, emb, ebuf);

  for (int t = 0; t < LSTEPS; ++t){
    gru_p1<<<NBLK, TPB, 0, stream>>>(wbuf, ebuf, hx, hf, bz, br, zbuf, rhx, t);
    gru_p2<<<NBLK, TPB, 0, stream>>>(wbuf, ebuf, rhx, zbuf, bh, hf, hx, out, t);
  }
}

// Round 8
// 6252.847 us; speedup vs baseline: 1.8354x; 1.4301x over previous
//
#include <hip/hip_runtime.h>

// GRU L=512, N=64, H=512, E=256, K=H+E=768. Persistent column-split kernel:
// 32 blocks x 256 threads; block b owns 16 output cols of z/r/h~; fp16 weight
// slices LDS-resident (73.7 KB, XOR-swizzled).
// Round 8 = round 4 (proven 5.41ms, per-wave dataflow, relaxed agent-scope
// atomic exchange, no fences, no __syncthreads in loop) + three fixes:
//  1. counter barrier: producers fetch_add one per-wave-group counter
//     (own 128B line); consumers poll ONE address (broadcast load) --
//     removes r4's 32-addr x 32-lane x 128-wave MALL poll storm.
//  2. out[t] stores moved AFTER the h publish+drain+arrive -- they drain
//     during the next poll instead of inside the critical vmcnt(0).
//  3. e-fragments for step t+1 prefetched into registers (32 VGPR) after
//     publishing h, hiding the ~0.5us MALL/HBM latency of cold ebuf reads
//     under the h-poll.
// Safety: vmcnt(0) before each arrival drains BOTH the wave's exchange
// stores and its exchange loads of the prior generation, so single-buffered
// hx/rhx can never be overwritten before all its readers are done (r4 rule).
// Numerics: fp16 operands, f32 MFMA accum, f32 state (absmax 3.9e-3 r1-r6).

#define LSTEPS 512
#define NBATCH 64
#define HDIM   512
#define EDIM   256
#define KDIM   768
#define NBLK   32
#define TPB    256

typedef _Float16 f16x8 __attribute__((ext_vector_type(8)));
typedef float    f32x4 __attribute__((ext_vector_type(4)));
typedef unsigned long long u64;

#define MFMA __builtin_amdgcn_mfma_f32_16x16x32_f16

__device__ __forceinline__ float sigm(float x){ return 1.0f/(1.0f+__expf(-x)); }
__device__ __forceinline__ float tanh_fast(float x){
  float e = __expf(2.0f*x);
  return 1.0f - 2.0f/(e + 1.0f);
}
__device__ __forceinline__ unsigned f16b(float x){
  union { _Float16 h; unsigned short u; } c; c.h = (_Float16)x; return (unsigned)c.u;
}

// Transpose+convert weights: wbuf[g][j][k] = fp16(W_g[k][j]); g in {z,r,h}.
__global__ void prep_w(const float* __restrict__ Wz, const float* __restrict__ Wr,
                       const float* __restrict__ Wh, _Float16* __restrict__ wbuf){
  int tid = blockIdx.x*256 + threadIdx.x;        // 3*512*768 = 1179648 threads
  int g   = tid / (HDIM*KDIM);
  int rem = tid - g*(HDIM*KDIM);
  int j   = rem / KDIM;
  int k   = rem - j*KDIM;
  const float* W = (g==0) ? Wz : ((g==1) ? Wr : Wh);
  wbuf[tid] = (_Float16)W[(size_t)k*HDIM + j];
}

// Gather embedding rows + convert: ebuf[t][n][k] = fp16(emb[x[t][n]][k]).
__global__ void prep_emb(const int* __restrict__ x, const float* __restrict__ emb,
                         _Float16* __restrict__ ebuf){
  int tid = blockIdx.x*256 + threadIdx.x;        // one float4 each
  int k4  = tid & 63;                            // E/4 = 64
  int tn  = tid >> 6;                            // 0..L*N-1
  int row = x[tn];
  const float4 v = *(const float4*)(emb + (size_t)row*EDIM + (k4<<2));
  union { _Float16 h[4]; uint2 u; } p;
  p.h[0] = (_Float16)v.x; p.h[1] = (_Float16)v.y;
  p.h[2] = (_Float16)v.z; p.h[3] = (_Float16)v.w;
  *(uint2*)(ebuf + (size_t)tn*EDIM + (k4<<2)) = p.u;
}

// Exchange store of (rows n0..n0+3, col jcol) as write-through 4B atomics.
// Lane pair (2q,2q+1) covers cols (j,j+1): shfl_xor repack -> even lane
// stores rows n0..n0+1, odd lane rows n0+2..n0+3, each one aligned dword.
__device__ __forceinline__ void store_x(_Float16* buf, int jc2, int n0, int lane,
                                        float v0, float v1, float v2, float v3){
  unsigned p01 = f16b(v0) | (f16b(v1) << 16);
  unsigned p23 = f16b(v2) | (f16b(v3) << 16);
  unsigned q01 = __shfl_xor(p01, 1, 64);
  unsigned q23 = __shfl_xor(p23, 1, 64);
  unsigned w0, w1; int r0;
  if (lane & 1){                       // own col = j+1 (high half of pair)
    w0 = (q23 & 0xffffu) | (p23 << 16);
    w1 = (q23 >> 16)     | (p23 & 0xffff0000u);
    r0 = n0 + 2;
  } else {                             // own col = j (low half)
    w0 = (p01 & 0xffffu) | (q01 << 16);
    w1 = (p01 >> 16)     | (q01 & 0xffff0000u);
    r0 = n0;
  }
  __hip_atomic_store((unsigned*)(buf + (size_t)r0*HDIM + jc2),     w0,
                     __ATOMIC_RELAXED, __HIP_MEMORY_SCOPE_AGENT);
  __hip_atomic_store((unsigned*)(buf + (size_t)(r0+1)*HDIM + jc2), w1,
                     __ATOMIC_RELAXED, __HIP_MEMORY_SCOPE_AGENT);
}

// Poll one per-wave-group counter until >= target. All lanes load the same
// address -> one memory transaction per wave per iteration (TCC broadcast).
__device__ __forceinline__ void waitcnt_ge(const unsigned* c, unsigned target){
  for (;;){
    unsigned v = __hip_atomic_load(c, __ATOMIC_RELAXED, __HIP_MEMORY_SCOPE_AGENT);
    if (v >= target) break;            // uniform branch (same value all lanes)
  }
}

__global__ __launch_bounds__(TPB, 1) void gru_persist(
    const _Float16* __restrict__ wbuf,   // [3][512][768] fp16 (col-major per gate)
    const _Float16* __restrict__ ebuf,   // [L][64][256] fp16
    const float* __restrict__ bz, const float* __restrict__ br, const float* __restrict__ bh,
    _Float16* __restrict__ hx,           // [64][512] fp16 exchange (h)
    _Float16* __restrict__ rhx,          // [64][512] fp16 exchange (r*h)
    unsigned* __restrict__ cnth,         // [4][32] h counters (wave-group stride 32)
    unsigned* __restrict__ cntrh,        // [4][32] rh counters
    float* __restrict__ out)             // [L][64][512] f32
{
  __shared__ char wlds[3*16*1536];       // 73728 B: [gate][col16][768 fp16]
  const int jbase = blockIdx.x * 16;

  // Stage weight slices -> LDS, XOR-swizzled by col to spread banks.
  for (int cidx = threadIdx.x; cidx < 3*16*96; cidx += TPB){
    int g   = cidx / (16*96);
    int rem = cidx - g*(16*96);
    int col = rem / 96;
    int kch = rem - col*96;              // 16B chunk index along K
    const uint4 v = *(const uint4*)(wbuf + ((size_t)(g*HDIM + jbase + col))*KDIM + kch*8);
    int off = (((g*16 + col)*1536) + kch*16) ^ ((col & 7) << 4);
    *(uint4*)(wlds + off) = v;
  }
  __syncthreads();                       // only barrier; loop below is per-wave

  const int lane = threadIdx.x & 63;
  const int wave = threadIdx.x >> 6;     // M-tile: rows 16*wave..16*wave+15
  const int c15  = lane & 15;
  const int kgrp = lane >> 4;
  const int jcol = jbase + c15;
  const int jc2  = jcol & ~1;
  const int arow = wave*16 + c15;        // A-fragment row (batch)
  const int n0   = wave*16 + kgrp*4;     // C/D row base (batch)
  const int swz  = (c15 & 7) << 4;
  const int linz = ((      c15)*1536) + kgrp*16;
  const int linr = ((16  + c15)*1536) + kgrp*16;
  const int linh = ((32  + c15)*1536) + kgrp*16;
  const float bzj = bz[jcol];
  const float brj = br[jcol];
  const float bhj = bh[jcol];
  unsigned* mycnth  = cnth  + wave*32;   // own 128B line per wave-group
  unsigned* mycntrh = cntrh + wave*32;
  const u64* hrow  = (const u64*)hx  + (size_t)arow*128 + kgrp*2;  // + kc*8 (+1)
  const u64* rhrow = (const u64*)rhx + (size_t)arow*128 + kgrp*2;
  float hreg[4] = {0.f, 0.f, 0.f, 0.f};  // private f32 hidden state

  u64 q[32];                              // one row-panel of A fragments
  f16x8 aereg[8];                         // e fragments for current step

#define LOADX(BASE) do {                                                      \
    _Pragma("unroll")                                                         \
    for (int kc = 0; kc < 16; ++kc){                                          \
      q[2*kc]   = __hip_atomic_load((BASE) + kc*8,     __ATOMIC_RELAXED,      \
                                    __HIP_MEMORY_SCOPE_AGENT);                \
      q[2*kc+1] = __hip_atomic_load((BASE) + kc*8 + 1, __ATOMIC_RELAXED,      \
                                    __HIP_MEMORY_SCOPE_AGENT);                \
    }                                                                         \
  } while (0)

#define AFRAG(KC) ({ union { u64 d[2]; f16x8 v; } _a;                         \
                     _a.d[0] = q[2*(KC)]; _a.d[1] = q[2*(KC)+1]; _a.v; })

  // Prefetch e fragments for t = 0.
  {
    const _Float16* ae0 = ebuf + (size_t)arow*EDIM + kgrp*8;
    #pragma unroll
    for (int kc = 0; kc < 8; ++kc) aereg[kc] = *(const f16x8*)(ae0 + kc*32);
  }

  for (int t = 0; t < LSTEPS; ++t){
    const unsigned tgt_h  = 32u*(unsigned)t;       // h(t) published
    const unsigned tgt_rh = 32u*(unsigned)(t + 1); // rh(t) published

    // ---- phase 1: r gate. e-part first (regs, no stall), then h exchange.
    f32x4 accr = {0.f,0.f,0.f,0.f};
    #pragma unroll
    for (int kc = 0; kc < 8; ++kc){
      f16x8 brv = *(const f16x8*)(wlds + ((linr + (16+kc)*64) ^ swz));
      accr = MFMA(aereg[kc], brv, accr, 0, 0, 0);
    }
    waitcnt_ge(mycnth, tgt_h);           // t=0: counters memset 0, passes
    LOADX(hrow);
    #pragma unroll
    for (int kc = 0; kc < 16; ++kc){
      f16x8 brv = *(const f16x8*)(wlds + ((linr + kc*64) ^ swz));
      accr = MFMA(AFRAG(kc), brv, accr, 0, 0, 0);
    }
    float rh[4];
    #pragma unroll
    for (int i = 0; i < 4; ++i)
      rh[i] = sigm(accr[i] + brj) * hreg[i];
    store_x(rhx, jc2, n0, lane, rh[0], rh[1], rh[2], rh[3]);
    asm volatile("s_waitcnt vmcnt(0)" ::: "memory");   // rh stores + h loads drained
    __builtin_amdgcn_sched_barrier(0);
    if (lane == 0)
      __hip_atomic_fetch_add(mycntrh, 1u,
                             __ATOMIC_RELAXED, __HIP_MEMORY_SCOPE_AGENT);

    // ---- cover the rh round-trip: z matmul (h frags in regs) + e-parts.
    f32x4 accz = {0.f,0.f,0.f,0.f};
    f32x4 acch = {0.f,0.f,0.f,0.f};
    #pragma unroll
    for (int kc = 0; kc < 16; ++kc){
      f16x8 bzv = *(const f16x8*)(wlds + ((linz + kc*64) ^ swz));
      accz = MFMA(AFRAG(kc), bzv, accz, 0, 0, 0);
    }
    #pragma unroll
    for (int kc = 0; kc < 8; ++kc){
      f16x8 bzv = *(const f16x8*)(wlds + ((linz + (16+kc)*64) ^ swz));
      f16x8 bhv = *(const f16x8*)(wlds + ((linh + (16+kc)*64) ^ swz));
      accz = MFMA(aereg[kc], bzv, accz, 0, 0, 0);
      acch = MFMA(aereg[kc], bhv, acch, 0, 0, 0);
    }
    float zreg[4];
    #pragma unroll
    for (int i = 0; i < 4; ++i) zreg[i] = sigm(accz[i] + bzj);

    // ---- phase 2: h~ h-part after rh exchange; epilogue; publish h.
    waitcnt_ge(mycntrh, tgt_rh);
    LOADX(rhrow);
    #pragma unroll
    for (int kc = 0; kc < 16; ++kc){
      f16x8 bhv = *(const f16x8*)(wlds + ((linh + kc*64) ^ swz));
      acch = MFMA(AFRAG(kc), bhv, acch, 0, 0, 0);
    }
    #pragma unroll
    for (int i = 0; i < 4; ++i){
      float ht = tanh_fast(acch[i] + bhj);
      hreg[i] = hreg[i] + zreg[i]*(ht - hreg[i]);    // (1-z)h + z*h~
    }
    store_x(hx, jc2, n0, lane, hreg[0], hreg[1], hreg[2], hreg[3]);
    asm volatile("s_waitcnt vmcnt(0)" ::: "memory");   // h stores + rh loads drained
    __builtin_amdgcn_sched_barrier(0);
    if (lane == 0)
      __hip_atomic_fetch_add(mycnth, 1u,
                             __ATOMIC_RELAXED, __HIP_MEMORY_SCOPE_AGENT);

    // ---- off the critical path: prefetch e(t+1), then write out[t].
    if (t + 1 < LSTEPS){
      const _Float16* aen = ebuf + ((size_t)(t+1)*NBATCH + arow)*EDIM + kgrp*8;
      #pragma unroll
      for (int kc = 0; kc < 8; ++kc) aereg[kc] = *(const f16x8*)(aen + kc*32);
    }
    #pragma unroll
    for (int i = 0; i < 4; ++i)
      out[((size_t)t*NBATCH + (n0+i))*HDIM + jcol] = hreg[i];
  }
#undef LOADX
#undef AFRAG
}

extern "C" void kernel_launch(void* const* d_in, const int* in_sizes, int n_in,
                              void* d_out, int out_size, void* d_ws, size_t ws_size,
                              hipStream_t stream) {
  const int*   x   = (const int*)  d_in[0];
  const float* emb = (const float*)d_in[1];
  const float* Wz  = (const float*)d_in[2];
  const float* bz  = (const float*)d_in[3];
  const float* Wr  = (const float*)d_in[4];
  const float* br  = (const float*)d_in[5];
  const float* Wh  = (const float*)d_in[6];
  const float* bh  = (const float*)d_in[7];
  float* out = (float*)d_out;
  char*  ws  = (char*)d_ws;

  size_t off = 0;
  unsigned* cnth  = (unsigned*)(ws + off); off += 4*32*4;                   // 512
  unsigned* cntrh = (unsigned*)(ws + off); off += 4*32*4;                   // 512
  _Float16* hx    = (_Float16*)(ws + off); off += (size_t)NBATCH*HDIM*2;    // 65536
  size_t zero_bytes = off;               // counters + hx must start at 0
  _Float16* rhx   = (_Float16*)(ws + off); off += (size_t)NBATCH*HDIM*2;    // 65536
  _Float16* wbuf  = (_Float16*)(ws + off); off += (size_t)3*HDIM*KDIM*2;    // 2359296
  _Float16* ebuf  = (_Float16*)(ws + off); off += (size_t)LSTEPS*NBATCH*EDIM*2; // 16777216

  hipMemsetAsync(ws, 0, zero_bytes, stream);

  prep_w  <<<(3*HDIM*KDIM)/256,          256, 0, stream>>>(Wz, Wr, Wh, wbuf);
  prep_emb<<<(LSTEPS*NBATCH*EDIM/4)/256, 256, 0, stream>>>(x, emb, ebuf);
  gru_persist<<<NBLK, TPB, 0, stream>>>(wbuf, ebuf, bz, br, bh,
                                        hx, rhx, cnth, cntrh, out);
}